// Round 7
// baseline (52.287 us; speedup 1.0000x reference)
//
#include <hip/hip_runtime.h>
#include <math.h>

#define BB 32
#define HH 56
#define WW 56
#define CC 256
#define KS 7
#define NPIX (BB * HH * WW)   // 100352
#define NQUAD (NPIX / 4)      // 25088 wave-jobs (4 pixels each)

typedef float vfloat4 __attribute__((ext_vector_type(4)));

// ---------------------------------------------------------------------------
// DPP wave64 reductions (rocPRIM pattern): no DS ops, pure VALU.
// ---------------------------------------------------------------------------
template <int CTRL, int RM, int BM>
__device__ __forceinline__ float dpp_add(float v) {
    const int iv = __float_as_int(v);
    const int sh = __builtin_amdgcn_update_dpp(iv, iv, CTRL, RM, BM, false);
    return v + __int_as_float(sh);
}
template <int CTRL, int RM, int BM>
__device__ __forceinline__ float dpp_max(float v) {
    const int iv = __float_as_int(v);
    const int sh = __builtin_amdgcn_update_dpp(iv, iv, CTRL, RM, BM, false);
    return fmaxf(v, __int_as_float(sh));
}

__device__ __forceinline__ float wave_sum(float s) {
    s = dpp_add<0x111, 0xf, 0xf>(s);  // row_shr:1
    s = dpp_add<0x112, 0xf, 0xf>(s);  // row_shr:2
    s = dpp_add<0x114, 0xf, 0xe>(s);  // row_shr:4
    s = dpp_add<0x118, 0xf, 0xc>(s);  // row_shr:8
    s = dpp_add<0x142, 0xa, 0xf>(s);  // row_bcast:15
    s = dpp_add<0x143, 0xc, 0xf>(s);  // row_bcast:31
    return __int_as_float(__builtin_amdgcn_readlane(__float_as_int(s), 63));
}
__device__ __forceinline__ float wave_max(float m) {
    m = dpp_max<0x111, 0xf, 0xf>(m);
    m = dpp_max<0x112, 0xf, 0xf>(m);
    m = dpp_max<0x114, 0xf, 0xe>(m);
    m = dpp_max<0x118, 0xf, 0xc>(m);
    m = dpp_max<0x142, 0xa, 0xf>(m);
    m = dpp_max<0x143, 0xc, 0xf>(m);
    return __int_as_float(__builtin_amdgcn_readlane(__float_as_int(m), 63));
}

// ---------------------------------------------------------------------------
// Kernel 1: avg+max pool, FOUR pixels per wave. Four independent coalesced
// 1KB loads issued back-to-back (4KB in flight per wave), 8 independent DPP
// reduce chains (pipeline), two 16B stores by lane 0.
// ---------------------------------------------------------------------------
__global__ __launch_bounds__(256) void pool_kernel(const float* __restrict__ x,
                                                   float4* __restrict__ pooled4) {
    const int wave = threadIdx.x >> 6;
    const int lane = threadIdx.x & 63;
    const int wid = blockIdx.x * 4 + wave;   // quad id, < NQUAD

    const size_t base = (size_t)wid * 256 + lane;
    const vfloat4* __restrict__ x4 = reinterpret_cast<const vfloat4*>(x);
    const vfloat4 v0 = x4[base];
    const vfloat4 v1 = x4[base + 64];
    const vfloat4 v2 = x4[base + 128];
    const vfloat4 v3 = x4[base + 192];

    float s0 = (v0.x + v0.y) + (v0.z + v0.w);
    float m0 = fmaxf(fmaxf(v0.x, v0.y), fmaxf(v0.z, v0.w));
    float s1 = (v1.x + v1.y) + (v1.z + v1.w);
    float m1 = fmaxf(fmaxf(v1.x, v1.y), fmaxf(v1.z, v1.w));
    float s2 = (v2.x + v2.y) + (v2.z + v2.w);
    float m2 = fmaxf(fmaxf(v2.x, v2.y), fmaxf(v2.z, v2.w));
    float s3 = (v3.x + v3.y) + (v3.z + v3.w);
    float m3 = fmaxf(fmaxf(v3.x, v3.y), fmaxf(v3.z, v3.w));

    s0 = wave_sum(s0); s1 = wave_sum(s1); s2 = wave_sum(s2); s3 = wave_sum(s3);
    m0 = wave_max(m0); m1 = wave_max(m1); m2 = wave_max(m2); m3 = wave_max(m3);

    if (lane == 0) {
        pooled4[wid * 2]     = make_float4(s0 * (1.0f / CC), m0, s1 * (1.0f / CC), m1);
        pooled4[wid * 2 + 1] = make_float4(s2 * (1.0f / CC), m2, s3 * (1.0f / CC), m3);
    }
}

// ---------------------------------------------------------------------------
// Kernel 2: fused conv+sigmoid+multiply, FOUR pixels per wave (adjacent cols,
// same row: pix0 = wid*4 so wcol0 is a multiple of 4 <= 52; +3 never wraps).
// Lanes 0..48 each take one 7x7 tap for all 4 pixels (adjacent pooled loads,
// L1-hot). DPP sum reduce, sigmoid, scale 4KB of x, store 4KB.
// ---------------------------------------------------------------------------
__global__ __launch_bounds__(256) void fused_kernel(const float* __restrict__ x,
                                                    const float2* __restrict__ pooled,
                                                    const float2* __restrict__ cwv,
                                                    float* __restrict__ out) {
    const int wave = threadIdx.x >> 6;
    const int lane = threadIdx.x & 63;
    const int wid = blockIdx.x * 4 + wave;

    // issue all 4 x loads first (independent of everything below)
    const size_t base = (size_t)wid * 256 + lane;
    const vfloat4* __restrict__ x4 = reinterpret_cast<const vfloat4*>(x);
    const vfloat4 v0 = x4[base];
    const vfloat4 v1 = x4[base + 64];
    const vfloat4 v2 = x4[base + 128];
    const vfloat4 v3 = x4[base + 192];

    const int pix0 = wid * 4;
    const int wcol0 = pix0 % WW;          // multiple of 4, <= 52
    const int t = pix0 / WW;
    const int hrow = t % HH;
    const int b = t / HH;

    float pa = 0.0f, pb = 0.0f, pc = 0.0f, pd = 0.0f;
    if (lane < KS * KS) {
        const int ky = lane / KS;
        const int kx = lane - ky * KS;
        const int yy = hrow + ky - 3;
        if (yy >= 0 && yy < HH) {
            const float2* __restrict__ row = pooled + ((size_t)b * HH + yy) * WW;
            const float2 w = cwv[lane];
            const int xx = wcol0 + kx - 3;
#define TAP(res, off)                                              \
            if ((unsigned)(xx + off) < WW) {                       \
                const float2 p = row[xx + off];                    \
                res = fmaf(p.x, w.x, p.y * w.y);                   \
            }
            TAP(pa, 0) TAP(pb, 1) TAP(pc, 2) TAP(pd, 3)
#undef TAP
        }
    }
    pa = wave_sum(pa); pb = wave_sum(pb); pc = wave_sum(pc); pd = wave_sum(pd);
    const float att0 = 1.0f / (1.0f + expf(-pa));
    const float att1 = 1.0f / (1.0f + expf(-pb));
    const float att2 = 1.0f / (1.0f + expf(-pc));
    const float att3 = 1.0f / (1.0f + expf(-pd));

    vfloat4* __restrict__ o4 = reinterpret_cast<vfloat4*>(out);
    o4[base]       = v0 * att0;
    o4[base + 64]  = v1 * att1;
    o4[base + 128] = v2 * att2;
    o4[base + 192] = v3 * att3;
}

extern "C" void kernel_launch(void* const* d_in, const int* in_sizes, int n_in,
                              void* d_out, int out_size, void* d_ws, size_t ws_size,
                              hipStream_t stream) {
    const float* x = (const float*)d_in[0];
    const float2* cw = (const float2*)d_in[1];
    float* out = (float*)d_out;
    float2* pooled = (float2*)d_ws;

    const int grid = NQUAD / 4;  // 6272 blocks, 4 wave-jobs each
    pool_kernel<<<grid, 256, 0, stream>>>(x, (float4*)pooled);
    fused_kernel<<<grid, 256, 0, stream>>>(x, pooled, cw, out);
}

// Round 9
// 51.417 us; speedup vs baseline: 1.0169x; 1.0169x over previous
//
#include <hip/hip_runtime.h>
#include <hip/hip_cooperative_groups.h>
#include <math.h>

#define BB 32
#define HH 56
#define WW 56
#define CC 256
#define KS 7
#define NPIX (BB * HH * WW)   // 100352

// coop config: 256 blocks x 512 threads = 2048 waves; 49 px/wave == NPIX.
// 1 block/CU -> co-residency needs only maxActiveBlocks >= 1.
#define NBLK 256
#define TPB 512
#define WPB 8                 // waves per block
#define PXW 49

// fallback (R6) config
#define NWPAIR (NPIX / 2)

typedef float vfloat4 __attribute__((ext_vector_type(4)));

namespace cg = cooperative_groups;

// ---------------------------------------------------------------------------
// DPP wave64 reductions: no DS ops, pure VALU.
// ---------------------------------------------------------------------------
template <int CTRL, int RM, int BM>
__device__ __forceinline__ float dpp_add(float v) {
    const int iv = __float_as_int(v);
    const int sh = __builtin_amdgcn_update_dpp(iv, iv, CTRL, RM, BM, false);
    return v + __int_as_float(sh);
}
template <int CTRL, int RM, int BM>
__device__ __forceinline__ float dpp_max(float v) {
    const int iv = __float_as_int(v);
    const int sh = __builtin_amdgcn_update_dpp(iv, iv, CTRL, RM, BM, false);
    return fmaxf(v, __int_as_float(sh));
}
__device__ __forceinline__ float wave_sum(float s) {
    s = dpp_add<0x111, 0xf, 0xf>(s);
    s = dpp_add<0x112, 0xf, 0xf>(s);
    s = dpp_add<0x114, 0xf, 0xe>(s);
    s = dpp_add<0x118, 0xf, 0xc>(s);
    s = dpp_add<0x142, 0xa, 0xf>(s);
    s = dpp_add<0x143, 0xc, 0xf>(s);
    return __int_as_float(__builtin_amdgcn_readlane(__float_as_int(s), 63));
}
__device__ __forceinline__ float wave_max(float m) {
    m = dpp_max<0x111, 0xf, 0xf>(m);
    m = dpp_max<0x112, 0xf, 0xf>(m);
    m = dpp_max<0x114, 0xf, 0xe>(m);
    m = dpp_max<0x118, 0xf, 0xc>(m);
    m = dpp_max<0x142, 0xa, 0xf>(m);
    m = dpp_max<0x143, 0xc, 0xf>(m);
    return __int_as_float(__builtin_amdgcn_readlane(__float_as_int(m), 63));
}

// ---------------------------------------------------------------------------
// Cooperative single kernel. Each wave owns 49 pixels; x stays in VGPRs
// across the grid sync so phase 2 re-reads NOTHING of x (saves 103MB VMEM).
// ---------------------------------------------------------------------------
__global__ __launch_bounds__(TPB, 2) void spatial_attn_all(
    const float* __restrict__ x,
    float2* __restrict__ pooled,
    const float2* __restrict__ cwv,
    float* __restrict__ out)
{
    const int wave = threadIdx.x >> 6;
    const int lane = threadIdx.x & 63;
    const int wid = blockIdx.x * WPB + wave;        // 0..2047

    const vfloat4* __restrict__ x4 = reinterpret_cast<const vfloat4*>(x);
    const size_t base = (size_t)wid * (PXW * 64) + lane;

    // ---- phase 1: load all 49 pixels into registers, pool ----
    vfloat4 a[PXW];
#pragma unroll
    for (int p = 0; p < PXW; ++p) {
        a[p] = x4[base + (size_t)p * 64];
    }

    const int pix0 = wid * PXW;
#pragma unroll
    for (int p = 0; p < PXW; ++p) {
        float s = (a[p].x + a[p].y) + (a[p].z + a[p].w);
        float m = fmaxf(fmaxf(a[p].x, a[p].y), fmaxf(a[p].z, a[p].w));
        s = wave_sum(s);
        m = wave_max(m);
        if (lane == 0) {
            pooled[pix0 + p] = make_float2(s * (1.0f / CC), m);
        }
    }

    cg::this_grid().sync();

    // ---- phase 2: conv + sigmoid from pooled; multiply from registers ----
    const bool active = lane < KS * KS;
    int ky = 0, kx = 0;
    float2 wgt = make_float2(0.0f, 0.0f);
    if (active) {
        ky = lane / KS;
        kx = lane - ky * KS;
        wgt = cwv[lane];
    }

#pragma unroll
    for (int p = 0; p < PXW; ++p) {
        const int pix = pix0 + p;
        const int wcol = pix % WW;
        const int t = pix / WW;
        const int hrow = t % HH;
        const int bimg = t / HH;

        float pa = 0.0f;
        if (active) {
            const int yy = hrow + ky - 3;
            const int xx = wcol + kx - 3;
            if ((unsigned)yy < HH && (unsigned)xx < WW) {
                const float2 pv = pooled[((size_t)bimg * HH + yy) * WW + xx];
                pa = fmaf(pv.x, wgt.x, pv.y * wgt.y);
            }
        }
        pa = wave_sum(pa);
        const float att = 1.0f / (1.0f + expf(-pa));

        reinterpret_cast<vfloat4*>(out)[base + (size_t)p * 64] = a[p] * att;
    }
}

// ---------------------------------------------------------------------------
// Fallback path (R6, 51.3us proven): two kernels, 2 px/wave.
// ---------------------------------------------------------------------------
__global__ __launch_bounds__(256) void pool_kernel(const float* __restrict__ x,
                                                   float4* __restrict__ pooled4) {
    const int wave = threadIdx.x >> 6;
    const int lane = threadIdx.x & 63;
    const int wid = blockIdx.x * 4 + wave;

    const size_t base = (size_t)wid * 128 + lane;
    const vfloat4 v0 = reinterpret_cast<const vfloat4*>(x)[base];
    const vfloat4 v1 = reinterpret_cast<const vfloat4*>(x)[base + 64];

    float s0 = (v0.x + v0.y) + (v0.z + v0.w);
    float m0 = fmaxf(fmaxf(v0.x, v0.y), fmaxf(v0.z, v0.w));
    float s1 = (v1.x + v1.y) + (v1.z + v1.w);
    float m1 = fmaxf(fmaxf(v1.x, v1.y), fmaxf(v1.z, v1.w));

    s0 = wave_sum(s0);
    s1 = wave_sum(s1);
    m0 = wave_max(m0);
    m1 = wave_max(m1);

    if (lane == 0) {
        pooled4[wid] = make_float4(s0 * (1.0f / CC), m0, s1 * (1.0f / CC), m1);
    }
}

__global__ __launch_bounds__(256) void fused_kernel(const float* __restrict__ x,
                                                    const float2* __restrict__ pooled,
                                                    const float2* __restrict__ cwv,
                                                    float* __restrict__ out) {
    const int wave = threadIdx.x >> 6;
    const int lane = threadIdx.x & 63;
    const int wid = blockIdx.x * 4 + wave;

    const size_t base = (size_t)wid * 128 + lane;
    const vfloat4 v0 = reinterpret_cast<const vfloat4*>(x)[base];
    const vfloat4 v1 = reinterpret_cast<const vfloat4*>(x)[base + 64];

    const int pix0 = wid * 2;
    const int wcol0 = pix0 % WW;
    const int t = pix0 / WW;
    const int hrow = t % HH;
    const int b = t / HH;

    float pa = 0.0f, pb = 0.0f;
    if (lane < KS * KS) {
        const int ky = lane / KS;
        const int kx = lane - ky * KS;
        const int yy = hrow + ky - 3;
        if (yy >= 0 && yy < HH) {
            const float2* __restrict__ row = pooled + ((size_t)b * HH + yy) * WW;
            const float2 w = cwv[lane];
            const int xx0 = wcol0 + kx - 3;
            const int xx1 = xx0 + 1;
            if (xx0 >= 0 && xx0 < WW) {
                const float2 p = row[xx0];
                pa = fmaf(p.x, w.x, p.y * w.y);
            }
            if (xx1 >= 0 && xx1 < WW) {
                const float2 p = row[xx1];
                pb = fmaf(p.x, w.x, p.y * w.y);
            }
        }
    }
    pa = wave_sum(pa);
    pb = wave_sum(pb);
    const float att0 = 1.0f / (1.0f + expf(-pa));
    const float att1 = 1.0f / (1.0f + expf(-pb));

    reinterpret_cast<vfloat4*>(out)[base]      = v0 * att0;
    reinterpret_cast<vfloat4*>(out)[base + 64] = v1 * att1;
}

extern "C" void kernel_launch(void* const* d_in, const int* in_sizes, int n_in,
                              void* d_out, int out_size, void* d_ws, size_t ws_size,
                              hipStream_t stream) {
    const float* x = (const float*)d_in[0];
    const float2* cw = (const float2*)d_in[1];
    float* out = (float*)d_out;
    float2* pooled = (float2*)d_ws;

    // Host-side, capture-safe, deterministic occupancy check: only take the
    // cooperative path if the runtime agrees >=1 block/CU fits (512 thr).
    int maxb = 0;
    hipError_t oe = hipOccupancyMaxActiveBlocksPerMultiprocessor(
        &maxb, (const void*)spatial_attn_all, TPB, 0);

    if (oe == hipSuccess && maxb >= 1) {
        void* args[] = {(void*)&x, (void*)&pooled, (void*)&cw, (void*)&out};
        hipLaunchCooperativeKernel((void*)spatial_attn_all, dim3(NBLK), dim3(TPB),
                                   args, 0, stream);
    } else {
        const int grid = NWPAIR / 4;  // 12544 blocks
        pool_kernel<<<grid, 256, 0, stream>>>(x, (float4*)pooled);
        fused_kernel<<<grid, 256, 0, stream>>>(x, pooled, cw, out);
    }
}